// Round 3
// baseline (527.147 us; speedup 1.0000x reference)
//
#include <hip/hip_runtime.h>

// ---------------- problem constants ----------------
constexpr int B_ = 2;
constexpr int C_ = 7;
constexpr int Dd = 32, Hh = 256, Ww = 256;
constexpr int V_ = Dd * Hh * Ww;          // 2097152
constexpr int NS_ = 17;                   // segments incl background
constexpr int NI_ = 16;                   // instances
constexpr int NBINS = 256;                // lovasz histogram bins over err in [0,2]
constexpr float BIN_SCALE = 128.0f;       // err * 128 -> bin
constexpr float INV_BIN = 1.0f / 128.0f;  // bin width

// stats fields per (b, s): 0 cnt | 1..3 sum xyz | 4..6 sum sig | 7..9 sum sig^2
//                          10 ccnt | 11..13 sum xyz*cf          (14 total)
constexpr int NF = 14;

__device__ __forceinline__ float vox_x(int v) { return (float)(v & 255) * (1.0f / 1023.0f); }
__device__ __forceinline__ float vox_y(int v) { return (float)((v >> 8) & 255) * (1.0f / 1023.0f); }
__device__ __forceinline__ float vox_z(int v) { return (float)(v >> 16) * (1.0f / 31.0f); }

// ---------------- kernel 1: segmented stats ----------------
__global__ __launch_bounds__(256) void k_stats(const float* __restrict__ pred,
                                               const int* __restrict__ inst,
                                               const int* __restrict__ cent,
                                               float* __restrict__ stats, int bpb) {
  // 64 LDS replicas, stride 239 (odd -> bank spread); [replica][17*14]
  __shared__ float h[64 * 239];
  const int tid = threadIdx.x;
  const int b = blockIdx.y;
  for (int i = tid; i < 64 * 239; i += 256) h[i] = 0.0f;
  __syncthreads();
  float* hb = h + (tid & 63) * 239;

  const float* p3 = pred + ((size_t)b * C_ + 3) * V_;
  const float* p4 = pred + ((size_t)b * C_ + 4) * V_;
  const float* p5 = pred + ((size_t)b * C_ + 5) * V_;
  const int* ib = inst + (size_t)b * V_;
  const int* cb = cent + (size_t)b * V_;

  const int stride = bpb * 256;
  for (int g = blockIdx.x * 256 + tid; g < V_ / 4; g += stride) {
    const float4 a = ((const float4*)p3)[g];
    const float4 bq = ((const float4*)p4)[g];
    const float4 c = ((const float4*)p5)[g];
    const int4 iv = ((const int4*)ib)[g];
    const int4 cv = ((const int4*)cb)[g];
    const float a0[4] = {a.x, a.y, a.z, a.w};
    const float a1[4] = {bq.x, bq.y, bq.z, bq.w};
    const float a2[4] = {c.x, c.y, c.z, c.w};
    const int iA[4] = {iv.x, iv.y, iv.z, iv.w};
    const int cA[4] = {cv.x, cv.y, cv.z, cv.w};
    const int v0 = g * 4;
#pragma unroll
    for (int j = 0; j < 4; ++j) {
      const int v = v0 + j;
      const float x = vox_x(v), y = vox_y(v), z = vox_z(v);
      const int s = iA[j];
      const float s0 = a0[j], s1 = a1[j], s2 = a2[j];
      float* hs = hb + s * NF;
      atomicAdd(hs + 0, 1.0f);
      atomicAdd(hs + 1, x);
      atomicAdd(hs + 2, y);
      atomicAdd(hs + 3, z);
      atomicAdd(hs + 4, s0);
      atomicAdd(hs + 5, s1);
      atomicAdd(hs + 6, s2);
      atomicAdd(hs + 7, s0 * s0);
      atomicAdd(hs + 8, s1 * s1);
      atomicAdd(hs + 9, s2 * s2);
      if (cA[j] != 0) {  // works for int32 0/1 and float32 1.0 encodings
        atomicAdd(hs + 10, 1.0f);
        atomicAdd(hs + 11, x);
        atomicAdd(hs + 12, y);
        atomicAdd(hs + 13, z);
      }
    }
  }
  __syncthreads();
  for (int t = tid; t < NS_ * NF; t += 256) {
    float acc = 0.0f;
    for (int r = 0; r < 64; ++r) acc += h[r * 239 + t];
    atomicAdd(&stats[b * (NS_ * NF) + t], acc);
  }
}

// ---------------- kernel 2: finalize per-instance params + var loss ----------------
__global__ void k_finalize(const float* __restrict__ stats, float* __restrict__ params,
                           float* __restrict__ Pcnt, float* __restrict__ out) {
  const int t = threadIdx.x;
  if (t >= B_ * NS_) return;
  const int b = t / NS_, s = t % NS_;
  const float* st = stats + (b * NS_ + s) * NF;
  const float cnt = st[0];
  const float inv = 1.0f / fmaxf(cnt, 1.0f);
  const float xm0 = st[1] * inv, xm1 = st[2] * inv, xm2 = st[3] * inv;
  const float sm0 = st[4] * inv, sm1 = st[5] * inv, sm2 = st[6] * inv;
  const float v0 = (st[7] - 2.0f * sm0 * st[4] + cnt * sm0 * sm0) * inv;
  const float v1 = (st[8] - 2.0f * sm1 * st[5] + cnt * sm1 * sm1) * inv;
  const float v2 = (st[9] - 2.0f * sm2 * st[6] + cnt * sm2 * sm2) * inv;
  if (s >= 1) {
    const float ccnt = st[10];
    const bool one = (ccnt == 1.0f);
    float* pp = params + (b * NI_ + (s - 1)) * 6;
    pp[0] = one ? st[11] : xm0;
    pp[1] = one ? st[12] : xm1;
    pp[2] = one ? st[13] : xm2;
    pp[3] = expf(10.0f * sm0);
    pp[4] = expf(10.0f * sm1);
    pp[5] = expf(10.0f * sm2);
    Pcnt[b * NI_ + (s - 1)] = cnt;
    // 0.5 (batch mean) * W_VAR(10) * (1/16) * mean_ch(var)
    const float varm = (v0 + v1 + v2) * (1.0f / 3.0f);
    atomicAdd(out, 0.3125f * varm);
  }
}

// ---------------- kernel 3: dist + histograms + seed loss ----------------
__global__ __launch_bounds__(512) void k_hist(const float* __restrict__ pred,
                                              const int* __restrict__ inst,
                                              const int* __restrict__ lab,
                                              const float* __restrict__ params,
                                              unsigned* __restrict__ bh,
                                              float* __restrict__ out, int bpb) {
  __shared__ unsigned hist[NI_ * 2 * NBINS];  // 32 KB
  __shared__ float red[2][8];
  const int tid = threadIdx.x;
  const int b = blockIdx.y;
  for (int i = tid; i < NI_ * 2 * NBINS; i += 512) hist[i] = 0u;
  __syncthreads();

  // per-instance params (uniform across block -> scalar regs)
  float pc0[NI_], pc1[NI_], pc2[NI_], ps0[NI_], ps1[NI_], ps2[NI_];
#pragma unroll
  for (int n = 0; n < NI_; ++n) {
    const float* pp = params + (b * NI_ + n) * 6;
    pc0[n] = pp[0]; pc1[n] = pp[1]; pc2[n] = pp[2];
    ps0[n] = pp[3]; ps1[n] = pp[4]; ps2[n] = pp[5];
  }

  const float* p0 = pred + ((size_t)b * C_ + 0) * V_;
  const float* p1 = pred + ((size_t)b * C_ + 1) * V_;
  const float* p2 = pred + ((size_t)b * C_ + 2) * V_;
  const float* p6 = pred + ((size_t)b * C_ + 6) * V_;
  const int* ib = inst + (size_t)b * V_;
  const int* lb = lab + (size_t)b * V_;

  float bgacc = 0.0f, fgacc = 0.0f;
  const int stride = bpb * 512;
  for (int g = blockIdx.x * 512 + tid; g < V_ / 4; g += stride) {
    const float4 f0 = ((const float4*)p0)[g];
    const float4 f1 = ((const float4*)p1)[g];
    const float4 f2 = ((const float4*)p2)[g];
    const float4 f6 = ((const float4*)p6)[g];
    const int4 iv = ((const int4*)ib)[g];
    const int4 lv = ((const int4*)lb)[g];
    const float a0[4] = {f0.x, f0.y, f0.z, f0.w};
    const float a1[4] = {f1.x, f1.y, f1.z, f1.w};
    const float a2[4] = {f2.x, f2.y, f2.z, f2.w};
    const float a6[4] = {f6.x, f6.y, f6.z, f6.w};
    const int iA[4] = {iv.x, iv.y, iv.z, iv.w};
    const int lA[4] = {lv.x, lv.y, lv.z, lv.w};
    const int v0 = g * 4;
#pragma unroll
    for (int j = 0; j < 4; ++j) {
      const int v = v0 + j;
      const float e0 = tanhf(a0[j]) + vox_x(v);
      const float e1 = tanhf(a1[j]) + vox_y(v);
      const float e2 = tanhf(a2[j]) + vox_z(v);
      const float sd = 1.0f / (1.0f + __expf(-a6[j]));
      const int is = iA[j];
      float down = 0.0f;
#pragma unroll
      for (int n = 0; n < NI_; ++n) {
        const float d0 = e0 - pc0[n];
        const float d1 = e1 - pc1[n];
        const float d2 = e2 - pc2[n];
        const float q = ps0[n] * d0 * d0 + ps1[n] * d1 * d1 + ps2[n] * d2 * d2;
        const float d = __expf(-q);
        const bool pos = (is == n + 1);
        if (pos) down = d;
        const float err = pos ? fmaf(-2.0f, d, 2.0f) : 2.0f * d;
        int bin = (int)(err * BIN_SCALE);
        bin = bin > NBINS - 1 ? NBINS - 1 : bin;
        atomicAdd(&hist[((n * 2 + (pos ? 1 : 0)) << 8) + bin], 1u);
      }
      if (lA[j] == 0) bgacc = fmaf(sd, sd, bgacc);
      if (is > 0) {
        const float tdiff = sd - down;
        fgacc = fmaf(tdiff, tdiff, fgacc);
      }
    }
  }

  // seed-loss block reduction
  float bgw = bgacc, fgw = fgacc;
  for (int off = 32; off > 0; off >>= 1) {
    bgw += __shfl_down(bgw, off);
    fgw += __shfl_down(fgw, off);
  }
  const int wid = tid >> 6;
  if ((tid & 63) == 0) { red[0][wid] = bgw; red[1][wid] = fgw; }
  __syncthreads();
  if (tid == 0) {
    float sb = 0.0f, sf = 0.0f;
    for (int w = 0; w < 512 / 64; ++w) { sb += red[0][w]; sf += red[1][w]; }
    // 0.5 (batch mean) * W_SEED(1) * (bg + FW(10)*fg) / V
    atomicAdd(out, 0.5f * (sb + 10.0f * sf) * (1.0f / (float)V_));
  }

  // flush per-block histogram (non-atomic, coalesced)
  unsigned* dst = bh + (size_t)(b * bpb + blockIdx.x) * (NI_ * 2 * NBINS);
  for (int i = tid; i < NI_ * 2 * NBINS; i += 512) dst[i] = hist[i];
}

// ---------------- kernel 4: reduce histograms + binned lovasz scan ----------------
__global__ __launch_bounds__(256) void k_lovasz(const unsigned* __restrict__ bh,
                                                const float* __restrict__ Pcnt,
                                                float* __restrict__ out, int bpb) {
  __shared__ unsigned hist2[2 * NBINS];  // [gt][bin]
  const int tid = threadIdx.x;
  const int b = blockIdx.x / NI_;
  const int n = blockIdx.x % NI_;
  for (int e = tid; e < 2 * NBINS; e += 256) {
    unsigned acc = 0;
    const unsigned* src = bh + (size_t)(b * bpb) * (NI_ * 2 * NBINS) + n * 2 * NBINS + e;
    for (int j = 0; j < bpb; ++j) acc += src[(size_t)j * (NI_ * 2 * NBINS)];
    hist2[e] = acc;
  }
  __syncthreads();
  if (tid == 0) {
    const float P = Pcnt[b * NI_ + n];
    float k = 0.0f, f = 0.0f, jprev = 0.0f, loss = 0.0f;
    for (int i = NBINS - 1; i >= 0; --i) {
      k += (float)hist2[NBINS + i];  // positives
      f += (float)hist2[i];          // negatives
      const float jnew = (k + f > 0.0f) ? (1.0f - (P - k) / (P + f)) : 0.0f;
      loss += ((float)i + 0.5f) * INV_BIN * (jnew - jprev);
      jprev = jnew;
    }
    // 0.5 (batch mean) * W_INST(1) * (1/16)
    atomicAdd(out, 0.5f * loss * (1.0f / 16.0f));
  }
}

// ---------------- launch ----------------
extern "C" void kernel_launch(void* const* d_in, const int* in_sizes, int n_in,
                              void* d_out, int out_size, void* d_ws, size_t ws_size,
                              hipStream_t stream) {
  const float* pred = (const float*)d_in[0];
  const int* inst = (const int*)d_in[1];
  const int* lab = (const int*)d_in[2];
  const int* cent = (const int*)d_in[3];
  float* out = (float*)d_out;

  float* stats = (float*)d_ws;                       // B*17*14 floats
  float* params = (float*)((char*)d_ws + 2048);      // B*16*6 floats
  float* Pcnt = (float*)((char*)d_ws + 4096);        // B*16 floats
  unsigned* bh = (unsigned*)((char*)d_ws + 8192);    // block histograms

  const size_t per_blk = (size_t)NI_ * 2 * NBINS * sizeof(unsigned);  // 8 KB
  int bpb3 = 256;
  if (ws_size > 8192) {
    const size_t avail = (ws_size - 8192) / (per_blk * B_);
    if ((size_t)bpb3 > avail) bpb3 = (int)avail;
  }
  if (bpb3 < 1) bpb3 = 1;

  hipMemsetAsync(d_ws, 0, 8192, stream);
  hipMemsetAsync(d_out, 0, sizeof(float), stream);

  k_stats<<<dim3(512, B_), 256, 0, stream>>>(pred, inst, cent, stats, 512);
  k_finalize<<<1, 64, 0, stream>>>(stats, params, Pcnt, out);
  k_hist<<<dim3(bpb3, B_), 512, 0, stream>>>(pred, inst, lab, params, bh, out, bpb3);
  k_lovasz<<<32, 256, 0, stream>>>(bh, Pcnt, out, bpb3);
}

// Round 6
// 455.496 us; speedup vs baseline: 1.1573x; 1.1573x over previous
//
#include <hip/hip_runtime.h>

typedef unsigned long long u64;

// ---------------- problem constants ----------------
constexpr int B_ = 2;
constexpr int C_ = 7;
constexpr int V_ = 32 * 256 * 256;        // 2097152
constexpr int NS_ = 17;                   // segments incl background
constexpr int NI_ = 16;                   // instances
constexpr int NBINS = 256;                // lovasz histogram bins over err in [0,2]
constexpr float BIN_SCALE = 128.0f;
constexpr float INV_BIN = 1.0f / 128.0f;

constexpr int NREP = 32;                  // LDS replicas in k_stats
constexpr int SEGSZ = NS_ * 5;            // 85 packed u64 per replica

// fixed-point scales
constexpr float QS = 8192.0f;             // (sig+8) scale (2^13)
constexpr float RS = 4096.0f;             // sig^2 scale   (2^12)
constexpr double SEED_SCALE = 16777216.0; // 2^24

__device__ __forceinline__ float vox_x(int v) { return (float)(v & 255) * (1.0f / 1023.0f); }
__device__ __forceinline__ float vox_y(int v) { return (float)((v >> 8) & 255) * (1.0f / 1023.0f); }
__device__ __forceinline__ float vox_z(int v) { return (float)(v >> 16) * (1.0f / 31.0f); }

// ---------------- kernel 1: segmented stats (integer, packed u64) ----------------
// statsI fields per (b,s): 0 cnt | 1 Sx | 2 Sy | 3 Sz | 4 Sq0 | 5 Sq1 | 6 Sq2 | 7 Sr0 | 8 Sr1 | 9 Sr2
__global__ __launch_bounds__(256) void k_stats(const float* __restrict__ pred,
                                               const int* __restrict__ inst,
                                               const int* __restrict__ cent,
                                               u64* __restrict__ statsI,
                                               u64* __restrict__ centI, int bpb) {
  __shared__ u64 sh[NREP * SEGSZ];  // 21760 B
  const int tid = threadIdx.x;
  const int b = blockIdx.y;
  for (int i = tid; i < NREP * SEGSZ; i += 256) sh[i] = 0ull;
  __syncthreads();
  u64* shr = sh + (tid & (NREP - 1)) * SEGSZ;

  const float* p3 = pred + ((size_t)b * C_ + 3) * V_;
  const float* p4 = pred + ((size_t)b * C_ + 4) * V_;
  const float* p5 = pred + ((size_t)b * C_ + 5) * V_;
  const int* ib = inst + (size_t)b * V_;
  const int* cb = cent + (size_t)b * V_;

  const int stride = bpb * 256;
  for (int g = blockIdx.x * 256 + tid; g < V_ / 4; g += stride) {
    const float4 a = ((const float4*)p3)[g];
    const float4 bq = ((const float4*)p4)[g];
    const float4 c = ((const float4*)p5)[g];
    const int4 iv = ((const int4*)ib)[g];
    const int4 cv = ((const int4*)cb)[g];
    const float a0[4] = {a.x, a.y, a.z, a.w};
    const float a1[4] = {bq.x, bq.y, bq.z, bq.w};
    const float a2[4] = {c.x, c.y, c.z, c.w};
    const int iA[4] = {iv.x, iv.y, iv.z, iv.w};
    const int cA[4] = {cv.x, cv.y, cv.z, cv.w};
    const int v0 = g * 4;
#pragma unroll
    for (int j = 0; j < 4; ++j) {
      const int v = v0 + j;
      const int xi = v & 255, yi = (v >> 8) & 255, zi = v >> 16;
      const int s = iA[j];
      const float s0 = fminf(fmaxf(a0[j], -8.0f), 8.0f);
      const float s1 = fminf(fmaxf(a1[j], -8.0f), 8.0f);
      const float s2 = fminf(fmaxf(a2[j], -8.0f), 8.0f);
      const int q0 = (int)rintf((s0 + 8.0f) * QS);  // 0..131072
      const int q1 = (int)rintf((s1 + 8.0f) * QS);
      const int q2 = (int)rintf((s2 + 8.0f) * QS);
      const int r0 = (int)rintf(s0 * s0 * RS);      // 0..262144
      const int r1 = (int)rintf(s1 * s1 * RS);
      const int r2 = (int)rintf(s2 * s2 * RS);
      u64* cc = shr + s * 5;
      atomicAdd(cc + 0, ((u64)xi << 40) | ((u64)yi << 16) | 1ull);
      atomicAdd(cc + 1, ((u64)q0 << 32) | (u64)zi);
      atomicAdd(cc + 2, ((u64)q1 << 32) | (u64)q2);
      atomicAdd(cc + 3, ((u64)r0 << 32) | (u64)r1);
      atomicAdd(cc + 4, (u64)r2);
      if (cA[j] != 0) {  // ~1 voxel per batch (bernoulli 2e-7)
        u64* ce = centI + (size_t)(b * NS_ + s) * 4;
        atomicAdd(ce + 0, 1ull);
        atomicAdd(ce + 1, (u64)xi);
        atomicAdd(ce + 2, (u64)yi);
        atomicAdd(ce + 3, (u64)zi);
      }
    }
  }
  __syncthreads();
  for (int t = tid; t < SEGSZ; t += 256) {
    u64 acc = 0;
    for (int r = 0; r < NREP; ++r) acc += sh[r * SEGSZ + t];
    const int seg = t / 5, f = t % 5;
    u64* dst = statsI + (size_t)(b * NS_ + seg) * 10;
    if (f == 0) {
      atomicAdd(dst + 0, acc & 0xFFFFull);          // cnt
      atomicAdd(dst + 1, acc >> 40);                // Sx
      atomicAdd(dst + 2, (acc >> 16) & 0xFFFFFFull);// Sy
    } else if (f == 1) {
      atomicAdd(dst + 3, acc & 0xFFFFFFFFull);      // Sz
      atomicAdd(dst + 4, acc >> 32);                // Sq0
    } else if (f == 2) {
      atomicAdd(dst + 5, acc >> 32);                // Sq1
      atomicAdd(dst + 6, acc & 0xFFFFFFFFull);      // Sq2
    } else if (f == 3) {
      atomicAdd(dst + 7, acc >> 32);                // Sr0
      atomicAdd(dst + 8, acc & 0xFFFFFFFFull);      // Sr1
    } else {
      atomicAdd(dst + 9, acc);                      // Sr2
    }
  }
}

// ---------------- kernel 2: finalize (fp64, plain stores) ----------------
__global__ void k_finalize(const u64* __restrict__ statsI, const u64* __restrict__ centI,
                           float* __restrict__ params, float* __restrict__ Pcnt,
                           float* __restrict__ varsum) {
  const int t = threadIdx.x;  // block = 64 (one wave)
  double varm = 0.0;
  if (t < B_ * NS_) {
    const int b = t / NS_, s = t % NS_;
    const u64* st = statsI + (size_t)(b * NS_ + s) * 10;
    const double cnt = (double)st[0];
    const double inv = 1.0 / fmax(cnt, 1.0);
    const double xm = (double)st[1] * (1.0 / 1023.0) * inv;
    const double ym = (double)st[2] * (1.0 / 1023.0) * inv;
    const double zm = (double)st[3] * (1.0 / 31.0) * inv;
    const double S0 = (double)st[4] * (1.0 / 8192.0) - 8.0 * cnt;  // sum sig0
    const double S1 = (double)st[5] * (1.0 / 8192.0) - 8.0 * cnt;
    const double S2 = (double)st[6] * (1.0 / 8192.0) - 8.0 * cnt;
    const double R0 = (double)st[7] * (1.0 / 4096.0);              // sum sig0^2
    const double R1 = (double)st[8] * (1.0 / 4096.0);
    const double R2 = (double)st[9] * (1.0 / 4096.0);
    const double m0 = S0 * inv, m1 = S1 * inv, m2 = S2 * inv;
    const double v0 = (R0 - 2.0 * m0 * S0 + cnt * m0 * m0) * inv;
    const double v1 = (R1 - 2.0 * m1 * S1 + cnt * m1 * m1) * inv;
    const double v2 = (R2 - 2.0 * m2 * S2 + cnt * m2 * m2) * inv;
    if (s >= 1) {
      const u64* ce = centI + (size_t)(b * NS_ + s) * 4;
      const bool one = (ce[0] == 1ull);
      float* pp = params + (b * NI_ + (s - 1)) * 6;
      pp[0] = (float)(one ? (double)ce[1] * (1.0 / 1023.0) : xm);
      pp[1] = (float)(one ? (double)ce[2] * (1.0 / 1023.0) : ym);
      pp[2] = (float)(one ? (double)ce[3] * (1.0 / 31.0) : zm);
      pp[3] = (float)exp(10.0 * m0);
      pp[4] = (float)exp(10.0 * m1);
      pp[5] = (float)exp(10.0 * m2);
      Pcnt[b * NI_ + (s - 1)] = (float)cnt;
      // 0.5 (batch mean) * W_VAR(10) * (1/16) * mean_ch(var)
      varm = 0.3125 * (v0 + v1 + v2) * (1.0 / 3.0);
    }
  }
  double acc = varm;
  for (int off = 32; off > 0; off >>= 1) acc += __shfl_down(acc, off);
  if (t == 0) *varsum = (float)acc;
}

// ---------------- kernel 3: dist + histograms + seed loss ----------------
__global__ __launch_bounds__(512) void k_hist(const float* __restrict__ pred,
                                              const int* __restrict__ inst,
                                              const int* __restrict__ lab,
                                              const float* __restrict__ params,
                                              unsigned* __restrict__ bh,
                                              u64* __restrict__ seedI, int bpb) {
  __shared__ unsigned hist[NI_ * 2 * NBINS];  // 32 KB
  __shared__ float red[2][8];
  const int tid = threadIdx.x;
  const int b = blockIdx.y;
  for (int i = tid; i < NI_ * 2 * NBINS; i += 512) hist[i] = 0u;
  __syncthreads();

  float pc0[NI_], pc1[NI_], pc2[NI_], ps0[NI_], ps1[NI_], ps2[NI_];
#pragma unroll
  for (int n = 0; n < NI_; ++n) {
    const float* pp = params + (b * NI_ + n) * 6;
    pc0[n] = pp[0]; pc1[n] = pp[1]; pc2[n] = pp[2];
    ps0[n] = pp[3]; ps1[n] = pp[4]; ps2[n] = pp[5];
  }

  const float* p0 = pred + ((size_t)b * C_ + 0) * V_;
  const float* p1 = pred + ((size_t)b * C_ + 1) * V_;
  const float* p2 = pred + ((size_t)b * C_ + 2) * V_;
  const float* p6 = pred + ((size_t)b * C_ + 6) * V_;
  const int* ib = inst + (size_t)b * V_;
  const int* lb = lab + (size_t)b * V_;

  float bgacc = 0.0f, fgacc = 0.0f;
  const int stride = bpb * 512;
  for (int g = blockIdx.x * 512 + tid; g < V_ / 4; g += stride) {
    const float4 f0 = ((const float4*)p0)[g];
    const float4 f1 = ((const float4*)p1)[g];
    const float4 f2 = ((const float4*)p2)[g];
    const float4 f6 = ((const float4*)p6)[g];
    const int4 iv = ((const int4*)ib)[g];
    const int4 lv = ((const int4*)lb)[g];
    const float a0[4] = {f0.x, f0.y, f0.z, f0.w};
    const float a1[4] = {f1.x, f1.y, f1.z, f1.w};
    const float a2[4] = {f2.x, f2.y, f2.z, f2.w};
    const float a6[4] = {f6.x, f6.y, f6.z, f6.w};
    const int iA[4] = {iv.x, iv.y, iv.z, iv.w};
    const int lA[4] = {lv.x, lv.y, lv.z, lv.w};
    const int v0 = g * 4;
#pragma unroll
    for (int j = 0; j < 4; ++j) {
      const int v = v0 + j;
      // fast tanh: 1 - 2/(e^{2x}+1)
      const float t0 = __expf(2.0f * a0[j]);
      const float t1 = __expf(2.0f * a1[j]);
      const float t2 = __expf(2.0f * a2[j]);
      const float e0 = 1.0f - 2.0f / (t0 + 1.0f) + vox_x(v);
      const float e1 = 1.0f - 2.0f / (t1 + 1.0f) + vox_y(v);
      const float e2 = 1.0f - 2.0f / (t2 + 1.0f) + vox_z(v);
      const float sd = 1.0f / (1.0f + __expf(-a6[j]));
      const int is = iA[j];
      float down = 0.0f;
#pragma unroll
      for (int n = 0; n < NI_; ++n) {
        const float d0 = e0 - pc0[n];
        const float d1 = e1 - pc1[n];
        const float d2 = e2 - pc2[n];
        const float q = ps0[n] * d0 * d0 + ps1[n] * d1 * d1 + ps2[n] * d2 * d2;
        const float d = __expf(-q);
        const bool pos = (is == n + 1);
        if (pos) down = d;
        const float err = pos ? fmaf(-2.0f, d, 2.0f) : 2.0f * d;
        int bin = (int)(err * BIN_SCALE);
        bin = bin > NBINS - 1 ? NBINS - 1 : bin;
        atomicAdd(&hist[((n * 2 + (pos ? 1 : 0)) << 8) + bin], 1u);
      }
      if (lA[j] == 0) bgacc = fmaf(sd, sd, bgacc);
      if (is > 0) {
        const float tdiff = sd - down;
        fgacc = fmaf(tdiff, tdiff, fgacc);
      }
    }
  }

  // seed-loss block reduction -> one u64 fixed-point atomic per block
  float bgw = bgacc, fgw = fgacc;
  for (int off = 32; off > 0; off >>= 1) {
    bgw += __shfl_down(bgw, off);
    fgw += __shfl_down(fgw, off);
  }
  const int wid = tid >> 6;
  if ((tid & 63) == 0) { red[0][wid] = bgw; red[1][wid] = fgw; }
  __syncthreads();
  if (tid == 0) {
    float sb = 0.0f, sf = 0.0f;
    for (int w = 0; w < 512 / 64; ++w) { sb += red[0][w]; sf += red[1][w]; }
    const double sacc = (double)sb + 10.0 * (double)sf;
    atomicAdd(seedI, (u64)(sacc * SEED_SCALE + 0.5));
  }

  // flush per-block histogram (non-atomic, coalesced)
  unsigned* dst = bh + (size_t)(b * bpb + blockIdx.x) * (NI_ * 2 * NBINS);
  for (int i = tid; i < NI_ * 2 * NBINS; i += 512) dst[i] = hist[i];
}

// ---------------- kernel 4: reduce histograms + binned lovasz scan ----------------
__global__ __launch_bounds__(256) void k_lovasz(const unsigned* __restrict__ bh,
                                                const float* __restrict__ Pcnt,
                                                float* __restrict__ losses, int bpb) {
  __shared__ unsigned hist2[2 * NBINS];
  const int tid = threadIdx.x;
  const int b = blockIdx.x / NI_;
  const int n = blockIdx.x % NI_;
  for (int e = tid; e < 2 * NBINS; e += 256) {
    unsigned acc = 0;
    const unsigned* src = bh + (size_t)(b * bpb) * (NI_ * 2 * NBINS) + n * 2 * NBINS + e;
    for (int j = 0; j < bpb; ++j) acc += src[(size_t)j * (NI_ * 2 * NBINS)];
    hist2[e] = acc;
  }
  __syncthreads();
  if (tid == 0) {
    const float P = Pcnt[b * NI_ + n];
    float k = 0.0f, f = 0.0f, jprev = 0.0f, loss = 0.0f;
    for (int i = NBINS - 1; i >= 0; --i) {
      k += (float)hist2[NBINS + i];  // positives
      f += (float)hist2[i];          // negatives
      const float jnew = (k + f > 0.0f) ? (1.0f - (P - k) / (P + f)) : 0.0f;
      loss += ((float)i + 0.5f) * INV_BIN * (jnew - jprev);
      jprev = jnew;
    }
    losses[b * NI_ + n] = loss;
  }
}

// ---------------- kernel 5: deterministic final sum ----------------
__global__ void k_final(const float* __restrict__ losses, const float* __restrict__ varsum,
                        const u64* __restrict__ seedI, float* __restrict__ out) {
  const int t = threadIdx.x;  // block = 64
  float v = (t < B_ * NI_) ? losses[t] : 0.0f;
  for (int off = 32; off > 0; off >>= 1) v += __shfl_down(v, off);
  if (t == 0) {
    const double total = (double)v * 0.03125                       // 0.5 * W_INST / 16
                       + (double)(*varsum)                          // already scaled
                       + (double)(*seedI) * (1.0 / SEED_SCALE) * 0.5 / (double)V_;
    out[0] = (float)total;
  }
}

// ---------------- launch ----------------
extern "C" void kernel_launch(void* const* d_in, const int* in_sizes, int n_in,
                              void* d_out, int out_size, void* d_ws, size_t ws_size,
                              hipStream_t stream) {
  const float* pred = (const float*)d_in[0];
  const int* inst = (const int*)d_in[1];
  const int* lab = (const int*)d_in[2];
  const int* cent = (const int*)d_in[3];
  float* out = (float*)d_out;

  char* ws = (char*)d_ws;
  u64* statsI = (u64*)(ws + 0);       // B*17*10 u64 = 2720 B
  u64* centI = (u64*)(ws + 4096);     // B*17*4 u64 = 1088 B
  float* params = (float*)(ws + 8192);   // B*16*6 f32
  float* Pcnt = (float*)(ws + 9216);     // B*16 f32
  float* varsum = (float*)(ws + 9472);   // 1 f32
  u64* seedI = (u64*)(ws + 9480);        // 1 u64
  float* losses = (float*)(ws + 9728);   // B*16 f32
  unsigned* bh = (unsigned*)(ws + 16384);

  const size_t per_blk = (size_t)NI_ * 2 * NBINS * sizeof(unsigned);  // 8 KB
  int bpb3 = 256;
  if (ws_size > 16384) {
    const size_t avail = (ws_size - 16384) / (per_blk * B_);
    if ((size_t)bpb3 > avail) bpb3 = (int)avail;
  }
  if (bpb3 < 1) bpb3 = 1;

  hipMemsetAsync(d_ws, 0, 16384, stream);

  k_stats<<<dim3(512, B_), 256, 0, stream>>>(pred, inst, cent, statsI, centI, 512);
  k_finalize<<<1, 64, 0, stream>>>(statsI, centI, params, Pcnt, varsum);
  k_hist<<<dim3(bpb3, B_), 512, 0, stream>>>(pred, inst, lab, params, bh, seedI, bpb3);
  k_lovasz<<<32, 256, 0, stream>>>(bh, Pcnt, losses, bpb3);
  k_final<<<1, 64, 0, stream>>>(losses, varsum, seedI, out);
}